// Round 2
// baseline (426.221 us; speedup 1.0000x reference)
//
#include <hip/hip_runtime.h>
#include <cstdint>

#define BATCH 4
#define SLEN  4096
#define FDIM  64
#define KDIM  32

// ---------------------------------------------------------------------------
// Kernel 1: V = X @ W   (row-major X [B*S,64], W [64,64]) -> ws V [B*S,64]
// ---------------------------------------------------------------------------
__global__ __launch_bounds__(256) void xw_kernel(const float* __restrict__ X,
                                                 const float* __restrict__ W,
                                                 float* __restrict__ V) {
    int idx = blockIdx.x * 256 + threadIdx.x;   // [0, B*S*64)
    int o   = idx & 63;
    int row = idx >> 6;
    const float* __restrict__ xr = X + (size_t)row * FDIM;   // wave-uniform row
    float s0 = 0.f, s1 = 0.f, s2 = 0.f, s3 = 0.f;
#pragma unroll
    for (int f = 0; f < FDIM; f += 4) {
        s0 = fmaf(xr[f + 0], W[(f + 0) * FDIM + o], s0);
        s1 = fmaf(xr[f + 1], W[(f + 1) * FDIM + o], s1);
        s2 = fmaf(xr[f + 2], W[(f + 2) * FDIM + o], s2);
        s3 = fmaf(xr[f + 3], W[(f + 3) * FDIM + o], s3);
    }
    V[idx] = (s0 + s1) + (s2 + s3);
}

// ---------------------------------------------------------------------------
// Kernel 2: flash-style partials over a key chunk. One wave per block; lane =
// one query of a 64-query tile. No max-subtraction: p = exp(relu(s)) (max s
// ~72, safely below fp32 overflow) -> partials are purely additive.
// Keys processed in PAIRS: both key rows and both value rows are issued
// before first dependent use -> ~12 wide loads in flight per wave.
// ---------------------------------------------------------------------------
__global__ __launch_bounds__(64) void attn_partial(const float* __restrict__ M,
                                                   const float* __restrict__ V,
                                                   float* __restrict__ accP,
                                                   float* __restrict__ lP,
                                                   int ksplit, int chunk) {
    const int qt   = blockIdx.x;
    const int b    = blockIdx.y;
    const int ks   = blockIdx.z;
    const int lane = threadIdx.x;
    const int q    = qt * 64 + lane;

    // This lane's query row (32 floats) in registers.
    const float* __restrict__ Mq = M + ((size_t)b * SLEN + q) * KDIM;
    float Q[KDIM];
#pragma unroll
    for (int k = 0; k < KDIM; k += 4) {
        float4 t = *reinterpret_cast<const float4*>(Mq + k);
        Q[k] = t.x; Q[k + 1] = t.y; Q[k + 2] = t.z; Q[k + 3] = t.w;
    }

    float acc[FDIM];
#pragma unroll
    for (int f = 0; f < FDIM; ++f) acc[f] = 0.f;
    float l = 0.f;

    const float* __restrict__ Mb = M + (size_t)b * SLEN * KDIM;
    const float* __restrict__ Vb = V + (size_t)b * SLEN * FDIM;

    const int j0 = ks * chunk;
    const int j1 = (j0 + chunk < SLEN) ? (j0 + chunk) : SLEN;

    for (int j = j0; j < j1; j += 2) {   // chunk is a multiple of 2
        const float4* __restrict__ kp0 =
            reinterpret_cast<const float4*>(Mb + (size_t)j * KDIM);
        const float4* __restrict__ kp1 =
            reinterpret_cast<const float4*>(Mb + (size_t)(j + 1) * KDIM);
        const float4* __restrict__ vp0 =
            reinterpret_cast<const float4*>(Vb + (size_t)j * FDIM);
        const float4* __restrict__ vp1 =
            reinterpret_cast<const float4*>(Vb + (size_t)(j + 1) * FDIM);

        // --- issue both key rows, then reduce ---
        float4 k0[KDIM / 4], k1[KDIM / 4];
#pragma unroll
        for (int k4 = 0; k4 < KDIM / 4; ++k4) k0[k4] = kp0[k4];
#pragma unroll
        for (int k4 = 0; k4 < KDIM / 4; ++k4) k1[k4] = kp1[k4];

        float a0 = 0.f, a1 = 0.f, a2 = 0.f, a3 = 0.f;
        float b0 = 0.f, b1 = 0.f, b2 = 0.f, b3 = 0.f;
#pragma unroll
        for (int k4 = 0; k4 < KDIM / 4; ++k4) {
            a0 = fmaf(Q[4 * k4 + 0], k0[k4].x, a0);
            a1 = fmaf(Q[4 * k4 + 1], k0[k4].y, a1);
            a2 = fmaf(Q[4 * k4 + 2], k0[k4].z, a2);
            a3 = fmaf(Q[4 * k4 + 3], k0[k4].w, a3);
            b0 = fmaf(Q[4 * k4 + 0], k1[k4].x, b0);
            b1 = fmaf(Q[4 * k4 + 1], k1[k4].y, b1);
            b2 = fmaf(Q[4 * k4 + 2], k1[k4].z, b2);
            b3 = fmaf(Q[4 * k4 + 3], k1[k4].w, b3);
        }
        float s0 = (a0 + a1) + (a2 + a3);
        float s1 = (b0 + b1) + (b2 + b3);
        float p0 = __expf(fmaxf(s0, 0.f));
        float p1 = __expf(fmaxf(s1, 0.f));
        l += p0 + p1;

        // --- issue both value rows, then accumulate ---
        float4 v0[FDIM / 4], v1[FDIM / 4];
#pragma unroll
        for (int f4 = 0; f4 < FDIM / 4; ++f4) v0[f4] = vp0[f4];
#pragma unroll
        for (int f4 = 0; f4 < FDIM / 4; ++f4) v1[f4] = vp1[f4];
#pragma unroll
        for (int f4 = 0; f4 < FDIM / 4; ++f4) {
            acc[4 * f4 + 0] = fmaf(p0, v0[f4].x, acc[4 * f4 + 0]);
            acc[4 * f4 + 1] = fmaf(p0, v0[f4].y, acc[4 * f4 + 1]);
            acc[4 * f4 + 2] = fmaf(p0, v0[f4].z, acc[4 * f4 + 2]);
            acc[4 * f4 + 3] = fmaf(p0, v0[f4].w, acc[4 * f4 + 3]);
        }
#pragma unroll
        for (int f4 = 0; f4 < FDIM / 4; ++f4) {
            acc[4 * f4 + 0] = fmaf(p1, v1[f4].x, acc[4 * f4 + 0]);
            acc[4 * f4 + 1] = fmaf(p1, v1[f4].y, acc[4 * f4 + 1]);
            acc[4 * f4 + 2] = fmaf(p1, v1[f4].z, acc[4 * f4 + 2]);
            acc[4 * f4 + 3] = fmaf(p1, v1[f4].w, acc[4 * f4 + 3]);
        }
    }

    const size_t pbase = ((size_t)b * SLEN + q) * (size_t)ksplit + ks;
    float4* __restrict__ ap = reinterpret_cast<float4*>(accP + pbase * FDIM);
#pragma unroll
    for (int f4 = 0; f4 < FDIM / 4; ++f4) {
        ap[f4] = make_float4(acc[4 * f4 + 0], acc[4 * f4 + 1],
                             acc[4 * f4 + 2], acc[4 * f4 + 3]);
    }
    lP[pbase] = l;
}

// ---------------------------------------------------------------------------
// Kernel 3: combine partials: out = V + (sum acc_i)/(sum l_i) + bias
// ---------------------------------------------------------------------------
__global__ __launch_bounds__(256) void combine_kernel(const float* __restrict__ V,
                                                      const float* __restrict__ accP,
                                                      const float* __restrict__ lP,
                                                      const float* __restrict__ bias,
                                                      float* __restrict__ out,
                                                      int ksplit) {
    int idx = blockIdx.x * 256 + threadIdx.x;   // [0, B*S*64)
    int o   = idx & 63;
    int row = idx >> 6;                          // b*S + q (wave-uniform)
    float num = 0.f, den = 0.f;
    for (int i = 0; i < ksplit; ++i) {
        num += accP[((size_t)row * ksplit + i) * FDIM + o];
        den += lP[(size_t)row * ksplit + i];     // wave-uniform -> s_load
    }
    out[idx] = V[idx] + num / den + bias[o];
}

// ---------------------------------------------------------------------------
extern "C" void kernel_launch(void* const* d_in, const int* in_sizes, int n_in,
                              void* d_out, int out_size, void* d_ws, size_t ws_size,
                              hipStream_t stream) {
    const float* X    = (const float*)d_in[0];   // [4,4096,64]
    const float* M    = (const float*)d_in[1];   // [4,4096,32]
    const float* W    = (const float*)d_in[2];   // [64,64]
    const float* bias = (const float*)d_in[3];   // [64]
    float* out = (float*)d_out;                  // [4,4096,64]

    const size_t vElems = (size_t)BATCH * SLEN * FDIM;   // 1,048,576

    // Largest key-split whose partial buffers fit in ws.
    // ksplit=16 -> 4096 waves -> 4 waves/SIMD (occupancy was the round-1 cap).
    int ksplit = 16;
    while (ksplit > 1) {
        size_t need = (vElems                         // V
                       + vElems * (size_t)ksplit      // accP
                       + (size_t)BATCH * SLEN * ksplit) // lP
                      * sizeof(float);
        if (need <= ws_size) break;
        ksplit >>= 1;
    }

    float* V    = (float*)d_ws;
    float* accP = V + vElems;
    float* lP   = accP + vElems * (size_t)ksplit;
    const int chunk = (SLEN + ksplit - 1) / ksplit;   // multiple of 2

    xw_kernel<<<(int)(vElems / 256), 256, 0, stream>>>(X, W, V);

    dim3 g2(SLEN / 64, BATCH, ksplit);
    attn_partial<<<g2, 64, 0, stream>>>(M, V, accP, lP, ksplit, chunk);

    combine_kernel<<<(int)(vElems / 256), 256, 0, stream>>>(V, accP, lP, bias,
                                                            out, ksplit);
}

// Round 3
// 182.971 us; speedup vs baseline: 2.3294x; 2.3294x over previous
//
#include <hip/hip_runtime.h>
#include <cstdint>

#define BATCH 4
#define SLEN  4096
#define FDIM  64
#define KDIM  32

typedef __attribute__((ext_vector_type(8))) short bf16x8;
typedef __attribute__((ext_vector_type(4))) float f32x4;

static __device__ __forceinline__ short f2bf(float f) {
    union { float f; unsigned u; } v; v.f = f;
    unsigned r = v.u + 0x7fffu + ((v.u >> 16) & 1u);   // RNE
    return (short)(r >> 16);
}
static __device__ __forceinline__ float bf2f(short s) {
    union { unsigned u; float f; } v;
    v.u = ((unsigned)(unsigned short)s) << 16;
    return v.f;
}

// ---------------------------------------------------------------------------
// M -> bf16 hi + bf16 lo (Dekker split): hi+lo reproduces M to ~2^-17 rel.
// ---------------------------------------------------------------------------
__global__ __launch_bounds__(256) void split_m(const float* __restrict__ M,
                                               short* __restrict__ Mhi,
                                               short* __restrict__ Mlo) {
    int idx = blockIdx.x * 256 + threadIdx.x;   // [0, B*S*32)
    float m = M[idx];
    short hi = f2bf(m);
    Mhi[idx] = hi;
    Mlo[idx] = f2bf(m - bf2f(hi));
}

// ---------------------------------------------------------------------------
// V = X @ W  (fp32, row-major [B*S,64])
// ---------------------------------------------------------------------------
__global__ __launch_bounds__(256) void xw_kernel(const float* __restrict__ X,
                                                 const float* __restrict__ W,
                                                 float* __restrict__ V) {
    int idx = blockIdx.x * 256 + threadIdx.x;   // [0, B*S*64)
    int o   = idx & 63;
    int row = idx >> 6;
    const float* __restrict__ xr = X + (size_t)row * FDIM;
    float s0 = 0.f, s1 = 0.f, s2 = 0.f, s3 = 0.f;
#pragma unroll
    for (int f = 0; f < FDIM; f += 4) {
        s0 = fmaf(xr[f + 0], W[(f + 0) * FDIM + o], s0);
        s1 = fmaf(xr[f + 1], W[(f + 1) * FDIM + o], s1);
        s2 = fmaf(xr[f + 2], W[(f + 2) * FDIM + o], s2);
        s3 = fmaf(xr[f + 3], W[(f + 3) * FDIM + o], s3);
    }
    V[idx] = (s0 + s1) + (s2 + s3);
}

// ---------------------------------------------------------------------------
// Vt[b][f][s] = bf16(V[b][s][f])  -- transposed copy for PV B-fragments.
// ---------------------------------------------------------------------------
__global__ __launch_bounds__(256) void transpose_v(const float* __restrict__ Vf,
                                                   short* __restrict__ Vt) {
    __shared__ float t[64][65];                  // +1 pad: conflict-free
    int b  = blockIdx.y;
    int s0 = blockIdx.x * 64;
    int c0 = threadIdx.x & 63;
    int r0 = threadIdx.x >> 6;
    const float* __restrict__ src = Vf + ((size_t)b * SLEN + s0) * FDIM;
#pragma unroll
    for (int i = 0; i < 16; ++i)
        t[r0 + i * 4][c0] = src[(size_t)(r0 + i * 4) * FDIM + c0];
    __syncthreads();
#pragma unroll
    for (int i = 0; i < 16; ++i) {
        int f = r0 + i * 4;
        Vt[((size_t)b * FDIM + f) * SLEN + s0 + c0] = f2bf(t[c0][f]);
    }
}

// ---------------------------------------------------------------------------
// Flash attention partials with MFMA. One wave = 16 queries; block = 4 waves
// (no inter-wave interaction, no __syncthreads). Keys in chunks of 32:
//   scores (2 tiles x 3 split-MFMAs, fp32 C) -> exp -> P bf16 via LDS
//   (C-layout -> A-layout) -> 4 PV MFMAs vs transposed V.
// Additive partials: p = exp(relu(s)) raw (max s ~72 < fp32 overflow).
// ---------------------------------------------------------------------------
__global__ __launch_bounds__(256) void attn_mfma(const short* __restrict__ Mhi,
                                                 const short* __restrict__ Mlo,
                                                 const short* __restrict__ Vt,
                                                 float* __restrict__ accP,
                                                 float* __restrict__ lP,
                                                 int ksplit, int chunk) {
    const int tid  = threadIdx.x;
    const int wave = tid >> 6;
    const int lane = tid & 63;
    const int col  = lane & 15;      // MFMA n / C-col index
    const int quad = lane >> 4;      // MFMA k-group / C-row-group
    const int b    = blockIdx.y;
    const int ks   = blockIdx.z;
    const int qbase = blockIdx.x * 64 + wave * 16;

    const short* __restrict__ Mbh = Mhi + (size_t)b * SLEN * KDIM;
    const short* __restrict__ Mbl = Mlo + (size_t)b * SLEN * KDIM;
    const short* __restrict__ Vb  = Vt  + (size_t)b * FDIM * SLEN;

    // Q A-fragments: A[m=lane&15][k=quad*8+j]
    bf16x8 Ah = *(const bf16x8*)(Mbh + (size_t)(qbase + col) * KDIM + quad * 8);
    bf16x8 Al = *(const bf16x8*)(Mbl + (size_t)(qbase + col) * KDIM + quad * 8);

    f32x4 accf[4];
#pragma unroll
    for (int fg = 0; fg < 4; ++fg) accf[fg] = (f32x4){0.f, 0.f, 0.f, 0.f};
    float lacc[4] = {0.f, 0.f, 0.f, 0.f};

    // P staging: 16 rows x 32 keys, row stride 40 bf16 (80 B: b128-aligned,
    // bank aliasing only 2-way = free).
    __shared__ short plds[4][16 * 40];
    short* __restrict__ pl = plds[wave];

    const int k0 = ks * chunk;
    for (int kt = k0; kt < k0 + chunk; kt += 32) {
        // Key B-fragments (B^T rows = M rows): B[n=lane&15][k=quad*8+j]
        const size_t off0 = (size_t)(kt + col) * KDIM + quad * 8;
        const size_t off1 = (size_t)(kt + 16 + col) * KDIM + quad * 8;
        bf16x8 Bh0 = *(const bf16x8*)(Mbh + off0);
        bf16x8 Bh1 = *(const bf16x8*)(Mbh + off1);
        bf16x8 Bl0 = *(const bf16x8*)(Mbl + off0);
        bf16x8 Bl1 = *(const bf16x8*)(Mbl + off1);

        f32x4 c0 = (f32x4){0.f, 0.f, 0.f, 0.f};
        f32x4 c1 = (f32x4){0.f, 0.f, 0.f, 0.f};
        c0 = __builtin_amdgcn_mfma_f32_16x16x32_bf16(Al, Bh0, c0, 0, 0, 0);
        c0 = __builtin_amdgcn_mfma_f32_16x16x32_bf16(Ah, Bl0, c0, 0, 0, 0);
        c0 = __builtin_amdgcn_mfma_f32_16x16x32_bf16(Ah, Bh0, c0, 0, 0, 0);
        c1 = __builtin_amdgcn_mfma_f32_16x16x32_bf16(Al, Bh1, c1, 0, 0, 0);
        c1 = __builtin_amdgcn_mfma_f32_16x16x32_bf16(Ah, Bl1, c1, 0, 0, 0);
        c1 = __builtin_amdgcn_mfma_f32_16x16x32_bf16(Ah, Bh1, c1, 0, 0, 0);

        // exp(relu(s)) in fp32; stage P as bf16 in A-layout source order.
        // C layout: row = quad*4 + j, col = lane&15; key = tile*16 + col.
#pragma unroll
        for (int j = 0; j < 4; ++j) {
            float p0 = __expf(fmaxf(c0[j], 0.f));
            float p1 = __expf(fmaxf(c1[j], 0.f));
            lacc[j] += p0 + p1;
            int row = quad * 4 + j;
            pl[row * 40 + col]      = f2bf(p0);
            pl[row * 40 + 16 + col] = f2bf(p1);
        }

        // P A-fragment: A[m=lane&15][k=quad*8+j] (same-wave LDS RAW; compiler
        // inserts lgkmcnt wait, DS ops are in program order per wave).
        bf16x8 Pa = *(const bf16x8*)(pl + col * 40 + quad * 8);

        // PV: B^T rows = Vt rows (f = fg*16 + lane&15), k = key in chunk.
#pragma unroll
        for (int fg = 0; fg < 4; ++fg) {
            bf16x8 Bv = *(const bf16x8*)(Vb + (size_t)(fg * 16 + col) * SLEN
                                         + kt + quad * 8);
            accf[fg] = __builtin_amdgcn_mfma_f32_16x16x32_bf16(Pa, Bv,
                                                               accf[fg],
                                                               0, 0, 0);
        }
    }

    // Epilogue: partial O (C-layout: row = quad*4+j, f = fg*16+col) and
    // partial l (reduce over the 16 cols this tile's lanes hold).
#pragma unroll
    for (int j = 0; j < 4; ++j) {
        int q = qbase + quad * 4 + j;
        size_t base = ((size_t)b * SLEN + q) * (size_t)ksplit + ks;
        float* __restrict__ op = accP + base * FDIM;
#pragma unroll
        for (int fg = 0; fg < 4; ++fg)
            op[fg * 16 + col] = accf[fg][j];
        float lv = lacc[j];
#pragma unroll
        for (int m = 1; m < 16; m <<= 1) lv += __shfl_xor(lv, m);
        if (col == 0) lP[base] = lv;
    }
}

// ---------------------------------------------------------------------------
// out = V + (sum acc_i)/(sum l_i) + bias
// ---------------------------------------------------------------------------
__global__ __launch_bounds__(256) void combine_kernel(const float* __restrict__ V,
                                                      const float* __restrict__ accP,
                                                      const float* __restrict__ lP,
                                                      const float* __restrict__ bias,
                                                      float* __restrict__ out,
                                                      int ksplit) {
    int idx = blockIdx.x * 256 + threadIdx.x;   // [0, B*S*64)
    int o   = idx & 63;
    int row = idx >> 6;
    float num = 0.f, den = 0.f;
    for (int i = 0; i < ksplit; ++i) {
        num += accP[((size_t)row * ksplit + i) * FDIM + o];
        den += lP[(size_t)row * ksplit + i];
    }
    out[idx] = V[idx] + num / den + bias[o];
}

// ---------------------------------------------------------------------------
extern "C" void kernel_launch(void* const* d_in, const int* in_sizes, int n_in,
                              void* d_out, int out_size, void* d_ws, size_t ws_size,
                              hipStream_t stream) {
    const float* X    = (const float*)d_in[0];   // [4,4096,64]
    const float* M    = (const float*)d_in[1];   // [4,4096,32]
    const float* W    = (const float*)d_in[2];   // [64,64]
    const float* bias = (const float*)d_in[3];   // [64]
    float* out = (float*)d_out;                  // [4,4096,64]

    const size_t vElems = (size_t)BATCH * SLEN * FDIM;   // 1,048,576
    const size_t mElems = (size_t)BATCH * SLEN * KDIM;   //   524,288
    const size_t rows   = (size_t)BATCH * SLEN;          //    16,384

    // Largest ksplit whose buffers fit in ws.
    int ksplit = 8;
    while (ksplit > 1) {
        size_t need = 4 * (vElems + vElems * (size_t)ksplit + rows * ksplit)
                    + 2 * (2 * mElems + vElems);
        if (need <= ws_size) break;
        ksplit >>= 1;
    }

    float* Vf   = (float*)d_ws;
    float* accP = Vf + vElems;
    float* lP   = accP + vElems * (size_t)ksplit;
    short* Mhi  = (short*)(lP + rows * (size_t)ksplit);
    short* Mlo  = Mhi + mElems;
    short* Vt   = Mlo + mElems;
    const int chunk = SLEN / ksplit;             // multiple of 32

    split_m<<<(int)(mElems / 256), 256, 0, stream>>>(M, Mhi, Mlo);
    xw_kernel<<<(int)(vElems / 256), 256, 0, stream>>>(X, W, Vf);
    transpose_v<<<dim3(SLEN / 64, BATCH), 256, 0, stream>>>(Vf, Vt);

    dim3 g(SLEN / 64, BATCH, ksplit);
    attn_mfma<<<g, 256, 0, stream>>>(Mhi, Mlo, Vt, accP, lP, ksplit, chunk);

    combine_kernel<<<(int)(vElems / 256), 256, 0, stream>>>(Vf, accP, lP, bias,
                                                            out, ksplit);
}

// Round 4
// 181.684 us; speedup vs baseline: 2.3459x; 1.0071x over previous
//
#include <hip/hip_runtime.h>
#include <cstdint>

#define BATCH  4
#define SLEN   4096
#define FDIM   64
#define KDIM   32
#define KSPLIT 8

typedef __attribute__((ext_vector_type(8))) short bf16x8;
typedef __attribute__((ext_vector_type(4))) float f32x4;

static __device__ __forceinline__ short f2bf(float f) {
    union { float f; unsigned u; } v; v.f = f;
    unsigned r = v.u + 0x7fffu + ((v.u >> 16) & 1u);   // RNE
    return (short)(r >> 16);
}
static __device__ __forceinline__ float bf2f(short s) {
    union { unsigned u; float f; } v;
    v.u = ((unsigned)(unsigned short)s) << 16;
    return v.f;
}
// pack2bf(a,b) -> uint with low short = bf16(a), high short = bf16(b), RNE.
static __device__ __forceinline__ unsigned pack2bf(float a, float b) {
    union { float f; unsigned u; } x, y; x.f = a; y.f = b;
    unsigned ra = x.u + 0x7fffu + ((x.u >> 16) & 1u);
    unsigned rb = y.u + 0x7fffu + ((y.u >> 16) & 1u);
    return __builtin_amdgcn_perm(rb, ra, 0x07060302u);  // {rb.hi, ra.hi}
}

// ---------------------------------------------------------------------------
// M -> bf16 hi + lo (Dekker split), vectorized float4 -> 2x ushort4.
// ---------------------------------------------------------------------------
__global__ __launch_bounds__(256) void split_m(const float4* __restrict__ M4,
                                               ushort4* __restrict__ H4,
                                               ushort4* __restrict__ L4) {
    int i = blockIdx.x * 256 + threadIdx.x;      // [0, B*S*32/4)
    float4 m = M4[i];
    ushort4 h, l;
    h.x = (unsigned short)f2bf(m.x); l.x = (unsigned short)f2bf(m.x - bf2f((short)h.x));
    h.y = (unsigned short)f2bf(m.y); l.y = (unsigned short)f2bf(m.y - bf2f((short)h.y));
    h.z = (unsigned short)f2bf(m.z); l.z = (unsigned short)f2bf(m.z - bf2f((short)h.z));
    h.w = (unsigned short)f2bf(m.w); l.w = (unsigned short)f2bf(m.w - bf2f((short)h.w));
    H4[i] = h; L4[i] = l;
}

// ---------------------------------------------------------------------------
// V = X @ W, float4 over the output dim (4 outputs/thread).
// ---------------------------------------------------------------------------
__global__ __launch_bounds__(256) void xw_kernel(const float* __restrict__ X,
                                                 const float4* __restrict__ W4,
                                                 float4* __restrict__ V4) {
    int i  = blockIdx.x * 256 + threadIdx.x;     // [0, B*S*16)
    int o4 = i & 15;
    int row = i >> 4;
    const float* __restrict__ xr = X + (size_t)row * FDIM;
    float4 acc = make_float4(0.f, 0.f, 0.f, 0.f);
#pragma unroll
    for (int f = 0; f < FDIM; ++f) {
        float4 w = W4[f * 16 + o4];
        float  x = xr[f];
        acc.x = fmaf(x, w.x, acc.x);
        acc.y = fmaf(x, w.y, acc.y);
        acc.z = fmaf(x, w.z, acc.z);
        acc.w = fmaf(x, w.w, acc.w);
    }
    V4[i] = acc;
}

// ---------------------------------------------------------------------------
// Vt[b][f][s0 + perm(c)] = bf16(V[b][s0+c][f]),
// perm within each 32-group: p = 2*(c&15) + ((c>>4)&1).  This matches the
// packed-pair P staging order in attn_mfma, so PV B-frags stay contiguous.
// ---------------------------------------------------------------------------
__global__ __launch_bounds__(256) void transpose_v(const float* __restrict__ Vf,
                                                   short* __restrict__ Vt) {
    __shared__ float t[64][65];
    int b  = blockIdx.y;
    int s0 = blockIdx.x * 64;
    int c0 = threadIdx.x & 63;
    int r0 = threadIdx.x >> 6;
    const float* __restrict__ src = Vf + ((size_t)b * SLEN + s0) * FDIM;
#pragma unroll
    for (int i = 0; i < 16; ++i)
        t[r0 + i * 4][c0] = src[(size_t)(r0 + i * 4) * FDIM + c0];
    __syncthreads();
    int pc = (c0 & 32) | (((c0 & 15) << 1) | ((c0 >> 4) & 1));
#pragma unroll
    for (int i = 0; i < 16; ++i) {
        int f = r0 + i * 4;
        Vt[((size_t)b * FDIM + f) * SLEN + s0 + pc] = f2bf(t[c0][f]);
    }
}

// ---------------------------------------------------------------------------
// Attention partials, MFMA, register-double-buffered.
// ---------------------------------------------------------------------------
struct Frags { bf16x8 h0, h1, l0, l1; bf16x8 v[4]; };

static __device__ __forceinline__ void load_frags(const short* __restrict__ Mbh,
                                                  const short* __restrict__ Mbl,
                                                  const short* __restrict__ Vb,
                                                  int kt, int col, int quad,
                                                  Frags& F) {
    int o0 = (kt + col) * KDIM + quad * 8;
    int o1 = o0 + 16 * KDIM;
    F.h0 = *(const bf16x8*)(Mbh + o0);
    F.h1 = *(const bf16x8*)(Mbh + o1);
    F.l0 = *(const bf16x8*)(Mbl + o0);
    F.l1 = *(const bf16x8*)(Mbl + o1);
    int vo = col * SLEN + kt + quad * 8;
#pragma unroll
    for (int fg = 0; fg < 4; ++fg)
        F.v[fg] = *(const bf16x8*)(Vb + fg * 16 * SLEN + vo);
}

static __device__ __forceinline__ void chunk_compute(const Frags& F,
                                                     unsigned* __restrict__ pl32,
                                                     const bf16x8 Ah, const bf16x8 Al,
                                                     f32x4 accf[4], float lacc[4],
                                                     int col, int quad) {
    f32x4 c0 = (f32x4){0.f, 0.f, 0.f, 0.f};
    f32x4 c1 = (f32x4){0.f, 0.f, 0.f, 0.f};
    c0 = __builtin_amdgcn_mfma_f32_16x16x32_bf16(Al, F.h0, c0, 0, 0, 0);
    c0 = __builtin_amdgcn_mfma_f32_16x16x32_bf16(Ah, F.l0, c0, 0, 0, 0);
    c0 = __builtin_amdgcn_mfma_f32_16x16x32_bf16(Ah, F.h0, c0, 0, 0, 0);
    c1 = __builtin_amdgcn_mfma_f32_16x16x32_bf16(Al, F.h1, c1, 0, 0, 0);
    c1 = __builtin_amdgcn_mfma_f32_16x16x32_bf16(Ah, F.l1, c1, 0, 0, 0);
    c1 = __builtin_amdgcn_mfma_f32_16x16x32_bf16(Ah, F.h1, c1, 0, 0, 0);

    // exp(relu(s)); pack (p0,p1) -> one dword at P-position 2*col{,+1}.
    // Row stride 20 dwords: quads hit bank sets {0..15,16..31,0..15,16..31}
    // + col -> exactly 2 lanes/bank = free.
#pragma unroll
    for (int j = 0; j < 4; ++j) {
        float p0 = __expf(fmaxf(c0[j], 0.f));
        float p1 = __expf(fmaxf(c1[j], 0.f));
        lacc[j] += p0 + p1;
        pl32[(quad * 4 + j) * 20 + col] = pack2bf(p0, p1);
    }

    // P A-fragment (same-wave LDS RAW: DS ops are in program order per wave).
    bf16x8 Pa = *(const bf16x8*)((const short*)pl32 + col * 40 + quad * 8);
#pragma unroll
    for (int fg = 0; fg < 4; ++fg)
        accf[fg] = __builtin_amdgcn_mfma_f32_16x16x32_bf16(Pa, F.v[fg],
                                                           accf[fg], 0, 0, 0);
}

__global__ __launch_bounds__(256, 4) void attn_mfma(const short* __restrict__ Mhi,
                                                    const short* __restrict__ Mlo,
                                                    const short* __restrict__ Vt,
                                                    float* __restrict__ accP,
                                                    float* __restrict__ lP) {
    const int tid  = threadIdx.x;
    const int wave = tid >> 6;
    const int lane = tid & 63;
    const int col  = lane & 15;
    const int quad = lane >> 4;
    const int b    = blockIdx.y;
    const int ks   = blockIdx.z;
    const int qbase = blockIdx.x * 64 + wave * 16;
    const int chunk = SLEN / KSPLIT;             // 512
    const int k0    = ks * chunk;

    const short* __restrict__ Mbh = Mhi + (size_t)b * SLEN * KDIM;
    const short* __restrict__ Mbl = Mlo + (size_t)b * SLEN * KDIM;
    const short* __restrict__ Vb  = Vt  + (size_t)b * FDIM * SLEN;

    bf16x8 Ah = *(const bf16x8*)(Mbh + (qbase + col) * KDIM + quad * 8);
    bf16x8 Al = *(const bf16x8*)(Mbl + (qbase + col) * KDIM + quad * 8);

    f32x4 accf[4];
#pragma unroll
    for (int fg = 0; fg < 4; ++fg) accf[fg] = (f32x4){0.f, 0.f, 0.f, 0.f};
    float lacc[4] = {0.f, 0.f, 0.f, 0.f};

    __shared__ unsigned plds[4][16 * 20];        // 5120 B
    unsigned* __restrict__ pl32 = plds[wave];

    Frags A, B;
    load_frags(Mbh, Mbl, Vb, k0, col, quad, A);
#pragma unroll 1
    for (int kt = k0; kt < k0 + chunk; kt += 64) {
        load_frags(Mbh, Mbl, Vb, kt + 32, col, quad, B);      // prefetch
        chunk_compute(A, pl32, Ah, Al, accf, lacc, col, quad);
        int ktn = (kt + 64 < k0 + chunk) ? kt + 64 : k0;      // safe wrap
        load_frags(Mbh, Mbl, Vb, ktn, col, quad, A);          // prefetch
        chunk_compute(B, pl32, Ah, Al, accf, lacc, col, quad);
    }

    // Epilogue: partial O (C-layout) + partial l (reduce 16 cols per row).
#pragma unroll
    for (int j = 0; j < 4; ++j) {
        int q = qbase + quad * 4 + j;
        size_t base = ((size_t)b * SLEN + q) * KSPLIT + ks;
        float* __restrict__ op = accP + base * FDIM;
#pragma unroll
        for (int fg = 0; fg < 4; ++fg)
            op[fg * 16 + col] = accf[fg][j];
        float lv = lacc[j];
#pragma unroll
        for (int m = 1; m < 16; m <<= 1) lv += __shfl_xor(lv, m);
        if (col == 0) lP[base] = lv;
    }
}

// ---------------------------------------------------------------------------
// out = V + (sum acc_i)/(sum l_i) + bias, float4.
// ---------------------------------------------------------------------------
__global__ __launch_bounds__(256) void combine_kernel(const float4* __restrict__ V4,
                                                      const float4* __restrict__ accP4,
                                                      const float* __restrict__ lP,
                                                      const float4* __restrict__ bias4,
                                                      float4* __restrict__ out4) {
    int i  = blockIdx.x * 256 + threadIdx.x;     // [0, B*S*16)
    int o4 = i & 15;
    int row = i >> 4;
    float nx = 0.f, ny = 0.f, nz = 0.f, nw = 0.f, den = 0.f;
#pragma unroll
    for (int k = 0; k < KSPLIT; ++k) {
        float4 a = accP4[((size_t)row * KSPLIT + k) * 16 + o4];
        nx += a.x; ny += a.y; nz += a.z; nw += a.w;
        den += lP[(size_t)row * KSPLIT + k];
    }
    float r = 1.f / den;
    float4 v = V4[i];
    float4 bb = bias4[o4];
    float4 o;
    o.x = v.x + nx * r + bb.x;
    o.y = v.y + ny * r + bb.y;
    o.z = v.z + nz * r + bb.z;
    o.w = v.w + nw * r + bb.w;
    out4[i] = o;
}

// ---------------------------------------------------------------------------
extern "C" void kernel_launch(void* const* d_in, const int* in_sizes, int n_in,
                              void* d_out, int out_size, void* d_ws, size_t ws_size,
                              hipStream_t stream) {
    const float* X    = (const float*)d_in[0];   // [4,4096,64]
    const float* M    = (const float*)d_in[1];   // [4,4096,32]
    const float* W    = (const float*)d_in[2];   // [64,64]
    const float* bias = (const float*)d_in[3];   // [64]
    float* out = (float*)d_out;                  // [4,4096,64]

    const size_t vElems = (size_t)BATCH * SLEN * FDIM;   // 1,048,576
    const size_t mElems = (size_t)BATCH * SLEN * KDIM;   //   524,288
    const size_t rows   = (size_t)BATCH * SLEN;          //    16,384

    // ws layout (~40.5 MB, proven to fit in R3):
    float* Vf   = (float*)d_ws;
    float* accP = Vf + vElems;
    float* lP   = accP + vElems * KSPLIT;
    short* Mhi  = (short*)(lP + rows * KSPLIT);
    short* Mlo  = Mhi + mElems;
    short* Vt   = Mlo + mElems;

    split_m<<<(int)(mElems / 1024), 256, 0, stream>>>(
        (const float4*)M, (ushort4*)Mhi, (ushort4*)Mlo);
    xw_kernel<<<(int)(vElems / 1024), 256, 0, stream>>>(
        X, (const float4*)W, (float4*)Vf);
    transpose_v<<<dim3(SLEN / 64, BATCH), 256, 0, stream>>>(Vf, Vt);

    dim3 g(SLEN / 64, BATCH, KSPLIT);
    attn_mfma<<<g, 256, 0, stream>>>(Mhi, Mlo, Vt, accP, lP);

    combine_kernel<<<(int)(vElems / 1024), 256, 0, stream>>>(
        (const float4*)Vf, (const float4*)accP, lP, (const float4*)bias,
        (float4*)out);
}